// Round 10
// baseline (54.313 us; speedup 1.0000x reference)
//
#include <hip/hip_runtime.h>

#define W 512

typedef float v4f __attribute__((ext_vector_type(4)));

// ---------------------------------------------------------------------------
// Fused kernel, 256 threads = 4 waves per block -> 8 blocks/CU resident.
// R9 lesson: nt stores regress (WRITE_SIZE +8%, FETCH unchanged) — reverted.
// R10 theory: the 43.5us plateau (4.6 TB/s vs 6.3 copy ceiling) is phase
// structure: with 1024-thread blocks only 2 blocks/CU were resident, so a
// col block's read-only phase 1 + barrier had little co-resident work to
// overlap. 8 small blocks/CU interleave col phase-1/phase-2 and row streams,
// keeping reads and writes in flight simultaneously throughout.
//
// Blocks [0, B*4): column scan (channel 1), explicit 2-pass (reload is
//   L2/L3-served, proven cheap in R4-R7). Tile = 128 cols x 512 rows.
//   Thread (c4 = t&31, seg = t>>5) owns 4 cols x 64 rows.
// Blocks [B*4, ...): row scan (channel 0). 4 waves/block, 4 rows per wave
//   (preamble amortized, 4 independent scans for ILP).
// ---------------------------------------------------------------------------
__global__ __launch_bounds__(256) void fused_scan_kernel(const float* __restrict__ in,
                                                         float* __restrict__ out,
                                                         int B) {
    __shared__ v4f sums[8][32];        // [segment][c4]  (4 KiB)

    const int nColBlocks = B * 4;      // 128-col tiles per image

    if ((int)blockIdx.x < nColBlocks) {
        // ----- column scan (channel 1) -----
        const int tile = blockIdx.x & 3;
        const int b    = blockIdx.x >> 2;
        const int c4   = threadIdx.x & 31;     // float4 column group
        const int seg  = threadIdx.x >> 5;     // 0..7, 64 rows each
        const int col  = tile * 128 + c4 * 4;

        const size_t base = (size_t)b * (2 * W * W) + (size_t)(W * W) + col
                          + (size_t)(seg * 64) * W;
        const v4f* __restrict__ p = (const v4f*)(in + base);
        v4f*       __restrict__ q = (v4f*)(out + base);
        const int sv = W / 4;                  // row stride in v4f units

        // Phase 1: segment sum (64 independent loads, high MLP)
        v4f acc = (v4f)(0.f);
#pragma unroll
        for (int y = 0; y < 64; ++y) acc += p[(size_t)y * sv];
        sums[seg][c4] = acc;
        __syncthreads();

        // Exclusive offset = sum of preceding segments' totals
        v4f off = (v4f)(0.f);
        for (int s = 0; s < seg; ++s) off += sums[s][c4];

        // Phase 2: reload (L2/L3-hot), running scan, plain store
#pragma unroll
        for (int y = 0; y < 64; ++y) {
            off += p[(size_t)y * sv];
            q[(size_t)y * sv] = off;
        }
    } else {
        // ----- row scan (channel 0), 4 rows per wave -----
        const int tx  = threadIdx.x & 63;      // lane
        const int wv  = threadIdx.x >> 6;      // wave 0..3
        const int rb  = (int)blockIdx.x - nColBlocks;
        const int row0 = (rb * 4 + wv) * 4;    // first of 4 consecutive rows

#pragma unroll
        for (int r = 0; r < 4; ++r) {
            const int row = row0 + r;
            const int b   = row >> 9;          // / 512
            const int y   = row & 511;         // % 512
            const size_t base = (size_t)b * (2 * W * W) + (size_t)y * W;

            const v4f* __restrict__ ip = (const v4f*)(in + base);
            v4f v0 = ip[tx * 2 + 0];
            v4f v1 = ip[tx * 2 + 1];

            float a0 = v0.x;
            float a1 = a0 + v0.y;
            float a2 = a1 + v0.z;
            float a3 = a2 + v0.w;
            float a4 = a3 + v1.x;
            float a5 = a4 + v1.y;
            float a6 = a5 + v1.z;
            float a7 = a6 + v1.w;

            float total = a7;
            float inc = total;
#pragma unroll
            for (int o = 1; o < 64; o <<= 1) {
                float t = __shfl_up(inc, o, 64);
                if (tx >= o) inc += t;
            }
            const float excl = inc - total;

            v4f r0 = { a0 + excl, a1 + excl, a2 + excl, a3 + excl };
            v4f r1 = { a4 + excl, a5 + excl, a6 + excl, a7 + excl };

            v4f* __restrict__ op = (v4f*)(out + base);
            op[tx * 2 + 0] = r0;
            op[tx * 2 + 1] = r1;
        }
    }
}

extern "C" void kernel_launch(void* const* d_in, const int* in_sizes, int n_in,
                              void* d_out, int out_size, void* d_ws, size_t ws_size,
                              hipStream_t stream) {
    const float* in = (const float*)d_in[0];
    float* out = (float*)d_out;

    const int B = in_sizes[0] / (2 * W * W);   // 64
    const int colBlocks = B * 4;               // 256  (128-col float4 tiles)
    const int rowBlocks = (B * W) / 16;        // 2048 (16 rows per block, 4/wave)

    fused_scan_kernel<<<colBlocks + rowBlocks, 256, 0, stream>>>(in, out, B);
}

// Round 11
// 44.708 us; speedup vs baseline: 1.2148x; 1.2148x over previous
//
#include <hip/hip_runtime.h>

#define W 512

typedef float v4f __attribute__((ext_vector_type(4)));

// ---------------------------------------------------------------------------
// Fused kernel, 256 threads = 4 waves per block, __launch_bounds__(256, 4)
// -> VGPR cap 128: enough for 16 float4 (64 VGPR) live across one barrier.
//
// R5/R6 failed register residency because the allocator's cap was 56-64;
// R10 failed because 64-rows/thread made the phase-2 reload L2-cold
// (FETCH 65->98 MB). R11: TRUE single-pass col scan with a SMALL live range:
// each col block walks its 128-col x 512-row strip in 4 sequential
// y-sub-tiles of 16 rows/thread, carrying the inter-sub-tile offset in a
// register. 32 VMEM/thread, no reload, no scratch.
//
// Blocks [0, B*4): column scan (channel 1). Thread (c4=t&31, seg=t>>5)
//   owns cols [4c4, 4c4+4) x rows [16seg, 16seg+16) within each sub-tile.
// Blocks [B*4, ...): row scan (channel 0), 4 waves/block, 2 rows/wave.
// ---------------------------------------------------------------------------
__global__ __launch_bounds__(256, 4) void fused_scan_kernel(const float* __restrict__ in,
                                                            float* __restrict__ out,
                                                            int B) {
    __shared__ v4f sums[8][32];        // [segment][c4]  (4 KiB)

    const int nColBlocks = B * 4;      // 128-col strips per image

    if ((int)blockIdx.x < nColBlocks) {
        // ----- column scan (channel 1), single-pass, 4 sequential sub-tiles -----
        const int tile = blockIdx.x & 3;
        const int b    = blockIdx.x >> 2;
        const int c4   = threadIdx.x & 31;     // float4 column group
        const int seg  = threadIdx.x >> 5;     // 0..7, 16 rows each
        const int col  = tile * 128 + c4 * 4;
        const int sv   = W / 4;                // row stride in v4f units

        const size_t base0 = (size_t)b * (2 * W * W) + (size_t)(W * W) + col;

        v4f strip = (v4f)(0.f);                // running offset for this column strip

        for (int t = 0; t < 4; ++t) {          // 4 sub-tiles of 128 rows
            const size_t rbase = base0 + (size_t)(t * 128 + seg * 16) * W;
            const v4f* __restrict__ p = (const v4f*)(in + rbase);
            v4f*       __restrict__ q = (v4f*)(out + rbase);

            v4f v[16];
#pragma unroll
            for (int y = 0; y < 16; ++y) v[y] = p[(size_t)y * sv];

            // in-register inclusive scan of the 16-row segment
            v4f acc = (v4f)(0.f);
#pragma unroll
            for (int y = 0; y < 16; ++y) { acc += v[y]; v[y] = acc; }

            // pin: forbid rematerialization of the loads across the barrier
#pragma unroll
            for (int y = 0; y < 16; ++y) {
                asm volatile("" : "+v"(v[y].x), "+v"(v[y].y), "+v"(v[y].z), "+v"(v[y].w));
            }

            sums[seg][c4] = acc;
            __syncthreads();

            // exclusive offset = strip offset + preceding segments' totals
            v4f off = strip;
            for (int s = 0; s < seg; ++s) off += sums[s][c4];

#pragma unroll
            for (int y = 0; y < 16; ++y) q[(size_t)y * sv] = v[y] + off;

            // advance strip offset by the whole sub-tile's column sums
            v4f tot = (v4f)(0.f);
#pragma unroll
            for (int s = 0; s < 8; ++s) tot += sums[s][c4];
            strip += tot;
            __syncthreads();                   // protect sums before next sub-tile
        }
    } else {
        // ----- row scan (channel 0), 2 rows per wave -----
        const int tx  = threadIdx.x & 63;      // lane
        const int wv  = threadIdx.x >> 6;      // wave 0..3
        const int rb  = (int)blockIdx.x - nColBlocks;
        const int row0 = (rb * 4 + wv) * 2;

#pragma unroll
        for (int r = 0; r < 2; ++r) {
            const int row = row0 + r;
            const int b   = row >> 9;          // / 512
            const int y   = row & 511;         // % 512
            const size_t base = (size_t)b * (2 * W * W) + (size_t)y * W;

            const v4f* __restrict__ ip = (const v4f*)(in + base);
            v4f v0 = ip[tx * 2 + 0];
            v4f v1 = ip[tx * 2 + 1];

            float a0 = v0.x;
            float a1 = a0 + v0.y;
            float a2 = a1 + v0.z;
            float a3 = a2 + v0.w;
            float a4 = a3 + v1.x;
            float a5 = a4 + v1.y;
            float a6 = a5 + v1.z;
            float a7 = a6 + v1.w;

            float total = a7;
            float inc = total;
#pragma unroll
            for (int o = 1; o < 64; o <<= 1) {
                float t = __shfl_up(inc, o, 64);
                if (tx >= o) inc += t;
            }
            const float excl = inc - total;

            v4f r0 = { a0 + excl, a1 + excl, a2 + excl, a3 + excl };
            v4f r1 = { a4 + excl, a5 + excl, a6 + excl, a7 + excl };

            v4f* __restrict__ op = (v4f*)(out + base);
            op[tx * 2 + 0] = r0;
            op[tx * 2 + 1] = r1;
        }
    }
}

extern "C" void kernel_launch(void* const* d_in, const int* in_sizes, int n_in,
                              void* d_out, int out_size, void* d_ws, size_t ws_size,
                              hipStream_t stream) {
    const float* in = (const float*)d_in[0];
    float* out = (float*)d_out;

    const int B = in_sizes[0] / (2 * W * W);   // 64
    const int colBlocks = B * 4;               // 256  (128-col strips)
    const int rowBlocks = (B * W) / 8;         // 4096 (8 rows per block, 2/wave)

    fused_scan_kernel<<<colBlocks + rowBlocks, 256, 0, stream>>>(in, out, B);
}